// Round 8
// baseline (124.008 us; speedup 1.0000x reference)
//
#include <hip/hip_runtime.h>
#include <hip/hip_bf16.h>

// Problem constants
#define B 64
#define D 25000
#define K 16
#define H 128
#define E 256
#define Z 32
#define DTILE 10
#define NBLK (D / DTILE)     // 2500 blocks
#define NREP 16              // replica accumulators (64 KB hot -> line-resident)
#define MSTR 68

// ws layout: rep f32[NREP*B*K] | hi f16[H*K] (pad 4KB) | Gh f16[D*H]
#define REP_BYTES (NREP * B * K * 4)          // 65536
#define HI_OFF    REP_BYTES
#define G_OFF     (REP_BYTES + 4096)
#define WS_NEEDED (G_OFF + (size_t)D * H * 2) // ~6.5 MB

typedef __attribute__((ext_vector_type(8))) _Float16 half8;
typedef __attribute__((ext_vector_type(2))) _Float16 hv2;
typedef __attribute__((ext_vector_type(4))) float f32x4;

// prep: blocks 0..15 zero replicas; block 16 builds fragment-ordered fp16 W2 table;
// blocks 17.. compute Gh[d][h] = fp16(feat_emb[d]@W1[1:17] + feat_bias[d]*W1[17] + b1)
__global__ __launch_bounds__(256) void prep_kernel(
    const float* __restrict__ W2, const float* __restrict__ feat_emb,
    const float* __restrict__ feat_bias, const float* __restrict__ W1,
    const float* __restrict__ b1, float* __restrict__ rep,
    _Float16* __restrict__ hi, _Float16* __restrict__ Gh)
{
    const int t = threadIdx.x;
    const int bid = blockIdx.x;
    if (bid < NREP) {
        for (int i = t; i < B * K; i += 256) rep[bid * B * K + i] = 0.f;
    } else if (bid == NREP) {
        for (int i = t; i < H * K; i += 256) {
            // i = ((s*4+g)*16+n)*8+j  ->  W2[(s*32+g*8+j)][n]
            int j = i & 7, n = (i >> 3) & 15, g = (i >> 7) & 3, s = i >> 9;
            int k = s * 32 + g * 8 + j;
            hi[i] = (_Float16)W2[k * K + n];
        }
    } else {
        int idx = (bid - NREP - 1) * 256 + t;   // < D*H by grid construction
        int d = idx >> 7, h = idx & (H - 1);
        float acc = fmaf(feat_bias[d], W1[17 * H + h], b1[h]);
        #pragma unroll
        for (int k = 0; k < K; ++k)
            acc = fmaf(feat_emb[d * K + k], W1[(1 + k) * H + h], acc);
        Gh[idx] = (_Float16)acc;
    }
}

// main: h1 = relu(x*w0 + G_d) in packed fp16 -> fp16 MFMA (b2 in C-init) ->
// c += mask * relu(.) in fp32, replica atomics. Hot loop: G from GLOBAL (L2),
// x in registers, only mask in LDS. Two dd chains in flight for ILP.
template <bool PRE>
__global__ __launch_bounds__(256) void partial_main_kernel(
    const float* __restrict__ x, const int* __restrict__ mask,
    const float* __restrict__ feat_emb, const float* __restrict__ feat_bias,
    const float* __restrict__ W1, const float* __restrict__ b1,
    const float* __restrict__ b2, const _Float16* __restrict__ Gh,
    const _Float16* __restrict__ hi, float* __restrict__ rep)
{
    __shared__ __align__(16) float sMf[DTILE * MSTR];          // mask only
    __shared__ __align__(16) _Float16 sGh[DTILE * H];          // fallback only

    const int t    = threadIdx.x;
    const int d0   = blockIdx.x * DTILE;
    const int lane = t & 63;
    const int wv   = t >> 6;
    const int g    = lane >> 4;
    const int n    = lane & 15;

    // stage mask transposed (only LDS tile)
    for (int i = t; i < DTILE * B; i += 256) {
        int bb = i / DTILE, dd = i - bb * DTILE;
        sMf[dd * MSTR + bb] = (float)mask[bb * D + d0 + dd];
    }
    if (!PRE) {
        for (int i = t; i < DTILE * H; i += 256) {
            int dd = i >> 7, h = i & (H - 1);
            int d = d0 + dd;
            float acc = fmaf(feat_bias[d], W1[17 * H + h], b1[h]);
            #pragma unroll
            for (int k = 0; k < K; ++k)
                acc = fmaf(feat_emb[d * K + k], W1[(1 + k) * H + h], acc);
            sGh[i] = (_Float16)acc;
        }
    }

    // per-lane x row (10 contiguous floats) -> fp16 register pairs
    const float* xrow = x + (size_t)(wv * 16 + n) * D + d0;    // 8B-aligned (d0*4 % 8 == 0)
    hv2 xh[DTILE / 2];
    #pragma unroll
    for (int i = 0; i < DTILE / 2; ++i) {
        float2 xv = *(const float2*)(xrow + 2 * i);
        xh[i] = (hv2){(_Float16)xv.x, (_Float16)xv.y};
    }

    // per-lane W2 fp16 fragments (prepped, coalesced) + w0 as fp16 pairs in regs
    half8 Bf[4];
    #pragma unroll
    for (int s = 0; s < 4; ++s)
        Bf[s] = *(const half8*)(hi + (((s * 4 + g) * 16 + n) << 3));
    hv2 w0h[4][4];
    #pragma unroll
    for (int s = 0; s < 4; ++s) {
        const float4* wp = (const float4*)&W1[s * 32 + g * 8];
        float4 a0 = wp[0], a1 = wp[1];
        w0h[s][0] = (hv2){(_Float16)a0.x, (_Float16)a0.y};
        w0h[s][1] = (hv2){(_Float16)a0.z, (_Float16)a0.w};
        w0h[s][2] = (hv2){(_Float16)a1.x, (_Float16)a1.y};
        w0h[s][3] = (hv2){(_Float16)a1.z, (_Float16)a1.w};
    }
    const float b2n = b2[n];
    const hv2 zeroh = {(_Float16)0.f, (_Float16)0.f};

    // G fragment base: global (PRE) or LDS (fallback) — template-constant select
    const _Float16* gb0;
    if (PRE) gb0 = Gh + (size_t)d0 * H + g * 8;
    else     gb0 = sGh + g * 8;
    __syncthreads();

    f32x4 cacc = {0.f, 0.f, 0.f, 0.f};
    const int moff = wv * 16 + g * 4;

    #pragma unroll
    for (int i = 0; i < DTILE / 2; ++i) {
        const int dd0 = 2 * i, dd1 = 2 * i + 1;
        const hv2 xa = {xh[i].x, xh[i].x};
        const hv2 xb = {xh[i].y, xh[i].y};
        f32x4 c1a = {b2n, b2n, b2n, b2n};
        f32x4 c1b = {b2n, b2n, b2n, b2n};
        #pragma unroll
        for (int s = 0; s < 4; ++s) {
            union GA { half8 v; hv2 p[4]; };
            GA ga, gb, A0, A1;
            ga.v = *(const half8*)(gb0 + dd0 * H + s * 32);   // global_load_dwordx4 (PRE)
            gb.v = *(const half8*)(gb0 + dd1 * H + s * 32);
            #pragma unroll
            for (int p = 0; p < 4; ++p) {
                hv2 h0 = __builtin_elementwise_fma(xa, w0h[s][p], ga.p[p]);
                hv2 h1 = __builtin_elementwise_fma(xb, w0h[s][p], gb.p[p]);
                A0.p[p] = __builtin_elementwise_max(h0, zeroh);
                A1.p[p] = __builtin_elementwise_max(h1, zeroh);
            }
            c1a = __builtin_amdgcn_mfma_f32_16x16x32_f16(A0.v, Bf[s], c1a, 0, 0, 0);
            c1b = __builtin_amdgcn_mfma_f32_16x16x32_f16(A1.v, Bf[s], c1b, 0, 0, 0);
        }
        const float4 mv0 = *(const float4*)&sMf[dd0 * MSTR + moff];
        const float4 mv1 = *(const float4*)&sMf[dd1 * MSTR + moff];
        cacc[0] = fmaf(mv0.x, fmaxf(c1a[0], 0.f), fmaf(mv1.x, fmaxf(c1b[0], 0.f), cacc[0]));
        cacc[1] = fmaf(mv0.y, fmaxf(c1a[1], 0.f), fmaf(mv1.y, fmaxf(c1b[1], 0.f), cacc[1]));
        cacc[2] = fmaf(mv0.z, fmaxf(c1a[2], 0.f), fmaf(mv1.z, fmaxf(c1b[2], 0.f), cacc[2]));
        cacc[3] = fmaf(mv0.w, fmaxf(c1a[3], 0.f), fmaf(mv1.w, fmaxf(c1b[3], 0.f), cacc[3]));
    }

    float* crep = rep + (size_t)(blockIdx.x & (NREP - 1)) * (B * K);
    #pragma unroll
    for (int r = 0; r < 4; ++r)
        atomicAdd(&crep[(moff + r) * K + n], cacc[r]);
}

// enc: reduce NREP replicas -> c[b], then 16->256->64 MLP. one block per sample.
__global__ __launch_bounds__(256) void partial_enc_kernel(
    const float* __restrict__ rep, const float* __restrict__ We1,
    const float* __restrict__ be1, const float* __restrict__ We2,
    const float* __restrict__ be2, float* __restrict__ out)
{
    const int b = blockIdx.x;
    const int t = threadIdx.x;
    __shared__ float sc[K];
    __shared__ float st1[E];
    __shared__ float red[256];

    {   // replica reduction: thread (grp=t>>4, k=t&15) reads replica grp
        const int k = t & 15, grp = t >> 4;
        red[t] = rep[grp * (B * K) + b * K + k];
    }
    __syncthreads();
    if (t < K) {
        float s2 = 0.f;
        #pragma unroll
        for (int q = 0; q < 16; ++q) s2 += red[q * 16 + t];
        sc[t] = s2;
    }
    __syncthreads();

    {
        float acc = be1[t];
        #pragma unroll
        for (int k = 0; k < K; ++k)
            acc = fmaf(sc[k], We1[k * E + t], acc);
        st1[t] = fmaxf(acc, 0.f);
    }
    __syncthreads();

    const int j = t & 63, seg = t >> 6;
    float acc = 0.f;
    #pragma unroll 4
    for (int e = seg * 64; e < seg * 64 + 64; ++e)
        acc = fmaf(st1[e], We2[e * 64 + j], acc);
    red[t] = acc;
    __syncthreads();

    if (t < 64) {
        float v = red[j] + red[64 + j] + red[128 + j] + red[192 + j] + be2[j];
        if (j < Z) out[b * Z + j] = v;                 // mu
        else       out[B * Z + b * Z + (j - Z)] = v;   // logvar
    }
}

extern "C" void kernel_launch(void* const* d_in, const int* in_sizes, int n_in,
                              void* d_out, int out_size, void* d_ws, size_t ws_size,
                              hipStream_t stream) {
    const float* x         = (const float*)d_in[0];
    const int*   mask      = (const int*)  d_in[1];
    const float* feat_emb  = (const float*)d_in[2];
    const float* feat_bias = (const float*)d_in[3];
    const float* W1        = (const float*)d_in[4];
    const float* b1        = (const float*)d_in[5];
    const float* W2        = (const float*)d_in[6];
    const float* b2        = (const float*)d_in[7];
    const float* We1       = (const float*)d_in[8];
    const float* be1       = (const float*)d_in[9];
    const float* We2       = (const float*)d_in[10];
    const float* be2       = (const float*)d_in[11];

    float*     rep = (float*)d_ws;
    _Float16*  hi  = (_Float16*)((char*)d_ws + HI_OFF);
    _Float16*  Gh  = (_Float16*)((char*)d_ws + G_OFF);

    const bool big = (ws_size >= WS_NEEDED);   // constant across calls
    const int  gblocks = big ? (D * H / 256) : 0;

    prep_kernel<<<NREP + 1 + gblocks, 256, 0, stream>>>(
        W2, feat_emb, feat_bias, W1, b1, rep, hi, Gh);
    if (big)
        partial_main_kernel<true><<<NBLK, 256, 0, stream>>>(
            x, mask, feat_emb, feat_bias, W1, b1, b2, Gh, hi, rep);
    else
        partial_main_kernel<false><<<NBLK, 256, 0, stream>>>(
            x, mask, feat_emb, feat_bias, W1, b1, b2, Gh, hi, rep);
    partial_enc_kernel<<<B, 256, 0, stream>>>(
        rep, We1, be1, We2, be2, (float*)d_out);
}

// Round 9
// 115.372 us; speedup vs baseline: 1.0749x; 1.0749x over previous
//
#include <hip/hip_runtime.h>
#include <hip/hip_bf16.h>

// Problem constants
#define B 64
#define D 25000
#define K 16
#define H 128
#define E 256
#define Z 32
#define DTILE 20
#define NBLK (D / DTILE)     // 1250 blocks -> single fully-resident round
#define NREP 8               // one replica per XCD (blockIdx&7 == XCD round-robin)
#define MSTR 68

// ws layout: rep f32[NREP*B*K] | hi f16[H*K]
#define REP_BYTES (NREP * B * K * 4)          // 32768
#define HI_OFF    REP_BYTES

typedef __attribute__((ext_vector_type(8))) _Float16 half8;
typedef __attribute__((ext_vector_type(2))) _Float16 hv2;
typedef __attribute__((ext_vector_type(4))) float f32x4;

// prep: blocks 0..7 zero replicas; block 8 builds fragment-ordered fp16 W2 table. Tiny.
__global__ __launch_bounds__(256) void prep_kernel(
    const float* __restrict__ W2, float* __restrict__ rep, _Float16* __restrict__ hi)
{
    const int t = threadIdx.x;
    const int bid = blockIdx.x;
    if (bid < NREP) {
        for (int i = t; i < B * K; i += 256) rep[bid * B * K + i] = 0.f;
    } else {
        for (int i = t; i < H * K; i += 256) {
            // i = ((s*4+g)*16+n)*8+j  ->  W2[(s*32+g*8+j)][n]
            int j = i & 7, n = (i >> 3) & 15, g = (i >> 7) & 3, s = i >> 9;
            int k = s * 32 + g * 8 + j;
            hi[i] = (_Float16)W2[k * K + n];
        }
    }
}

// main: G computed in-block (fp32->fp16, LDS); h1 = relu(x*w0 + G) packed fp16;
// h2 = relu(h1@W2 + b2) via fp16 MFMA (b2 in C-init); c += mask*h2 fp32 -> XCD-local replica atomics.
__global__ __launch_bounds__(256) void partial_main_kernel(
    const float* __restrict__ x, const int* __restrict__ mask,
    const float* __restrict__ feat_emb, const float* __restrict__ feat_bias,
    const float* __restrict__ W1, const float* __restrict__ b1,
    const float* __restrict__ b2, const _Float16* __restrict__ hi,
    float* __restrict__ rep)
{
    __shared__ __align__(16) _Float16 sGh[DTILE * H];   // 5 KB
    __shared__ __align__(16) float sMf[DTILE * MSTR];   // 5.4 KB

    const int t    = threadIdx.x;
    const int d0   = blockIdx.x * DTILE;
    const int lane = t & 63;
    const int wv   = t >> 6;
    const int g    = lane >> 4;
    const int n    = lane & 15;

    // stage mask transposed
    for (int i = t; i < DTILE * B; i += 256) {
        int bb = i / DTILE, dd = i - bb * DTILE;
        sMf[dd * MSTR + bb] = (float)mask[bb * D + d0 + dd];
    }
    // G tile in-block: G[dd][h] = feat_emb[d]@W1[1:17] + feat_bias[d]*W1[17] + b1
    for (int i = t; i < DTILE * H; i += 256) {
        int dd = i >> 7, h = i & (H - 1);
        int d = d0 + dd;
        float acc = fmaf(feat_bias[d], W1[17 * H + h], b1[h]);
        #pragma unroll
        for (int k = 0; k < K; ++k)
            acc = fmaf(feat_emb[d * K + k], W1[(1 + k) * H + h], acc);
        sGh[i] = (_Float16)acc;
    }

    // per-lane x row (20 contiguous floats, 16B-aligned since d0*4 % 16 == 0) -> fp16 pairs
    const float* xrow = x + (size_t)(wv * 16 + n) * D + d0;
    hv2 xh[DTILE / 2];
    #pragma unroll
    for (int i = 0; i < DTILE / 4; ++i) {
        float4 xv = *(const float4*)(xrow + 4 * i);
        xh[2 * i]     = (hv2){(_Float16)xv.x, (_Float16)xv.y};
        xh[2 * i + 1] = (hv2){(_Float16)xv.z, (_Float16)xv.w};
    }

    // per-lane W2 fp16 fragments (prepped, coalesced) + w0 as fp16 pairs in regs
    half8 Bf[4];
    #pragma unroll
    for (int s = 0; s < 4; ++s)
        Bf[s] = *(const half8*)(hi + (((s * 4 + g) * 16 + n) << 3));
    hv2 w0h[4][4];
    #pragma unroll
    for (int s = 0; s < 4; ++s) {
        const float4* wp = (const float4*)&W1[s * 32 + g * 8];
        float4 a0 = wp[0], a1 = wp[1];
        w0h[s][0] = (hv2){(_Float16)a0.x, (_Float16)a0.y};
        w0h[s][1] = (hv2){(_Float16)a0.z, (_Float16)a0.w};
        w0h[s][2] = (hv2){(_Float16)a1.x, (_Float16)a1.y};
        w0h[s][3] = (hv2){(_Float16)a1.z, (_Float16)a1.w};
    }
    const float b2n = b2[n];
    const hv2 zeroh = {(_Float16)0.f, (_Float16)0.f};
    __syncthreads();

    f32x4 cacc = {0.f, 0.f, 0.f, 0.f};
    const int moff = wv * 16 + g * 4;
    const _Float16* gb0 = sGh + g * 8;

    #pragma unroll
    for (int i = 0; i < DTILE / 2; ++i) {
        const int dd0 = 2 * i, dd1 = 2 * i + 1;
        const hv2 xa = {xh[i].x, xh[i].x};
        const hv2 xb = {xh[i].y, xh[i].y};
        f32x4 c1a = {b2n, b2n, b2n, b2n};
        f32x4 c1b = {b2n, b2n, b2n, b2n};
        #pragma unroll
        for (int s = 0; s < 4; ++s) {
            union GA { half8 v; hv2 p[4]; };
            GA ga, gb, A0, A1;
            ga.v = *(const half8*)(gb0 + dd0 * H + s * 32);   // ds_read_b128
            gb.v = *(const half8*)(gb0 + dd1 * H + s * 32);
            #pragma unroll
            for (int p = 0; p < 4; ++p) {
                hv2 h0 = __builtin_elementwise_fma(xa, w0h[s][p], ga.p[p]);
                hv2 h1 = __builtin_elementwise_fma(xb, w0h[s][p], gb.p[p]);
                A0.p[p] = __builtin_elementwise_max(h0, zeroh);
                A1.p[p] = __builtin_elementwise_max(h1, zeroh);
            }
            c1a = __builtin_amdgcn_mfma_f32_16x16x32_f16(A0.v, Bf[s], c1a, 0, 0, 0);
            c1b = __builtin_amdgcn_mfma_f32_16x16x32_f16(A1.v, Bf[s], c1b, 0, 0, 0);
        }
        const float4 mv0 = *(const float4*)&sMf[dd0 * MSTR + moff];
        const float4 mv1 = *(const float4*)&sMf[dd1 * MSTR + moff];
        cacc[0] = fmaf(mv0.x, fmaxf(c1a[0], 0.f), fmaf(mv1.x, fmaxf(c1b[0], 0.f), cacc[0]));
        cacc[1] = fmaf(mv0.y, fmaxf(c1a[1], 0.f), fmaf(mv1.y, fmaxf(c1b[1], 0.f), cacc[1]));
        cacc[2] = fmaf(mv0.z, fmaxf(c1a[2], 0.f), fmaf(mv1.z, fmaxf(c1b[2], 0.f), cacc[2]));
        cacc[3] = fmaf(mv0.w, fmaxf(c1a[3], 0.f), fmaf(mv1.w, fmaxf(c1b[3], 0.f), cacc[3]));
    }

    // XCD-local replica: block i dispatches to XCD i%8 (round-robin), so replica
    // blockIdx&7 is only ever touched from one XCD -> atomics stay in local L2.
    float* crep = rep + (size_t)(blockIdx.x & (NREP - 1)) * (B * K);
    #pragma unroll
    for (int r = 0; r < 4; ++r)
        atomicAdd(&crep[(moff + r) * K + n], cacc[r]);
}

// enc: reduce NREP replicas -> c[b], then 16->256->64 MLP. one block per sample.
__global__ __launch_bounds__(256) void partial_enc_kernel(
    const float* __restrict__ rep, const float* __restrict__ We1,
    const float* __restrict__ be1, const float* __restrict__ We2,
    const float* __restrict__ be2, float* __restrict__ out)
{
    const int b = blockIdx.x;
    const int t = threadIdx.x;
    __shared__ float sc[K];
    __shared__ float st1[E];
    __shared__ float red[256];

    {   // replica reduction (8 replicas; grp>=8 contributes 0)
        const int k = t & 15, grp = t >> 4;
        red[t] = (grp < NREP) ? rep[grp * (B * K) + b * K + k] : 0.f;
    }
    __syncthreads();
    if (t < K) {
        float s2 = 0.f;
        #pragma unroll
        for (int q = 0; q < 16; ++q) s2 += red[q * 16 + t];
        sc[t] = s2;
    }
    __syncthreads();

    {
        float acc = be1[t];
        #pragma unroll
        for (int k = 0; k < K; ++k)
            acc = fmaf(sc[k], We1[k * E + t], acc);
        st1[t] = fmaxf(acc, 0.f);
    }
    __syncthreads();

    const int j = t & 63, seg = t >> 6;
    float acc = 0.f;
    #pragma unroll 4
    for (int e = seg * 64; e < seg * 64 + 64; ++e)
        acc = fmaf(st1[e], We2[e * 64 + j], acc);
    red[t] = acc;
    __syncthreads();

    if (t < 64) {
        float v = red[j] + red[64 + j] + red[128 + j] + red[192 + j] + be2[j];
        if (j < Z) out[b * Z + j] = v;                 // mu
        else       out[B * Z + b * Z + (j - Z)] = v;   // logvar
    }
}

extern "C" void kernel_launch(void* const* d_in, const int* in_sizes, int n_in,
                              void* d_out, int out_size, void* d_ws, size_t ws_size,
                              hipStream_t stream) {
    const float* x         = (const float*)d_in[0];
    const int*   mask      = (const int*)  d_in[1];
    const float* feat_emb  = (const float*)d_in[2];
    const float* feat_bias = (const float*)d_in[3];
    const float* W1        = (const float*)d_in[4];
    const float* b1        = (const float*)d_in[5];
    const float* W2        = (const float*)d_in[6];
    const float* b2        = (const float*)d_in[7];
    const float* We1       = (const float*)d_in[8];
    const float* be1       = (const float*)d_in[9];
    const float* We2       = (const float*)d_in[10];
    const float* be2       = (const float*)d_in[11];

    float*     rep = (float*)d_ws;
    _Float16*  hi  = (_Float16*)((char*)d_ws + HI_OFF);

    prep_kernel<<<NREP + 1, 256, 0, stream>>>(W2, rep, hi);
    partial_main_kernel<<<NBLK, 256, 0, stream>>>(
        x, mask, feat_emb, feat_bias, W1, b1, b2, hi, rep);
    partial_enc_kernel<<<B, 256, 0, stream>>>(
        rep, We1, be1, We2, be2, (float*)d_out);
}